// Round 2
// baseline (1057.781 us; speedup 1.0000x reference)
//
#include <hip/hip_runtime.h>
#include <stdint.h>

// QuantLinear: x[4,2048,4096] fp32, int4-packed W [11008,4096], group=128.
// Pipeline: (1) per-token int8 fake-quant -> q8 + scales in ws
//           (2) unpack int4 -> int8 (nibble - zero) in ws
//           (3) i8 MFMA GEMM with per-group fp32 scaling + bias epilogue.

#define IN_F 4096
#define OUT_F 11008
#define GS 128

#define BM 128
#define BN 128
#define BK 128                 // one quant group per K-step
#define NKT (IN_F / BK)        // 32

using i32x4 = __attribute__((ext_vector_type(4))) int;
using f32x4 = __attribute__((ext_vector_type(4))) float;

// ---------------- Kernel 1: per-token activation fake-quant ----------------
__global__ __launch_bounds__(256) void act_quant_kernel(
    const float* __restrict__ x, int8_t* __restrict__ q, float* __restrict__ sc) {
  __shared__ float wmax[4];
  const int tok = blockIdx.x;
  const int tid = threadIdx.x;
  const float* xr = x + (size_t)tok * IN_F + tid * 16;

  f32x4 v[4];
  float am = 0.f;
#pragma unroll
  for (int i = 0; i < 4; ++i) {
    v[i] = *(const f32x4*)(xr + i * 4);
#pragma unroll
    for (int j = 0; j < 4; ++j) am = fmaxf(am, fabsf(v[i][j]));
  }
#pragma unroll
  for (int off = 1; off < 64; off <<= 1) am = fmaxf(am, __shfl_xor(am, off));
  if ((tid & 63) == 0) wmax[tid >> 6] = am;
  __syncthreads();
  am = fmaxf(fmaxf(wmax[0], wmax[1]), fmaxf(wmax[2], wmax[3]));
  const float scale = fmaxf(am, 1e-5f) / 127.0f;

  i32x4 pk;
#pragma unroll
  for (int i = 0; i < 4; ++i) {
    uint32_t w = 0;
#pragma unroll
    for (int j = 0; j < 4; ++j) {
      float r = rintf(v[i][j] / scale);          // round-half-even == jnp.round
      r = fminf(fmaxf(r, -128.f), 127.f);
      int iv = (int)r;
      w |= (uint32_t)(iv & 255) << (8 * j);
    }
    pk[i] = (int)w;
  }
  *(i32x4*)(q + (size_t)tok * IN_F + tid * 16) = pk;
  if (tid == 0) sc[tok] = scale;
}

// ---------------- Kernel 2: unpack int4 -> int8 (nibble - zero) ----------------
// qweight: one byte value per int32. flat weight f: byte b=f/2, even=hi nibble, odd=lo.
// group g = f/128 = b/64. Thread handles 8 bytes = 16 weights (same group).
__global__ __launch_bounds__(256) void unpack_kernel(
    const int* __restrict__ qw, const int* __restrict__ wz, int8_t* __restrict__ w8) {
  const int t = blockIdx.x * 256 + threadIdx.x;     // 0 .. 2,818,047
  const int z = wz[t >> 3];
  const i32x4 a = *(const i32x4*)(qw + (size_t)t * 8);
  const i32x4 b = *(const i32x4*)(qw + (size_t)t * 8 + 4);
  int vals[8];
#pragma unroll
  for (int i = 0; i < 4; ++i) { vals[i] = a[i]; vals[4 + i] = b[i]; }
  i32x4 outw;
#pragma unroll
  for (int h = 0; h < 4; ++h) {
    const int x0 = vals[2 * h], x1 = vals[2 * h + 1];
    const int w0 = ((x0 >> 4) & 15) - z;
    const int w1 = (x0 & 15) - z;
    const int w2 = ((x1 >> 4) & 15) - z;
    const int w3 = (x1 & 15) - z;
    outw[h] = (w0 & 255) | ((w1 & 255) << 8) | ((w2 & 255) << 16) | ((w3 & 255) << 24);
  }
  *(i32x4*)(w8 + (size_t)t * 16) = outw;
}

// ---------------- Kernel 3: i8 GEMM with per-group scaling ----------------
// A = q8 [M][K] int8 row-major; B = w8 [N][K] int8 row-major (i.e. B^T form).
// 128x128 tile, 4 waves each 64x64 (4x4 frags of 16x16), BK=128 = one group.
// LDS tiles XOR-swizzled (byte ^= (row&7)<<4) via pre-swizzled global source
// (global_load_lds dest must stay linear), same XOR applied on ds_read.
__global__ __launch_bounds__(256) void gemm_kernel(
    const int8_t* __restrict__ Aq, const int8_t* __restrict__ Bq,
    const float* __restrict__ asc, const float* __restrict__ wsc,
    const float* __restrict__ bias, float* __restrict__ out) {
  __shared__ int8_t As[BM * BK];       // 16 KiB
  __shared__ int8_t Bs[BN * BK];       // 16 KiB
  __shared__ float Ws[NKT * BN];       // 16 KiB: Ws[g][col]

  const int tid = threadIdx.x;
  const int lane = tid & 63;
  const int wid = tid >> 6;
  const int bm0 = blockIdx.y * BM;
  const int bn0 = blockIdx.x * BN;
  const int wm = (wid >> 1) * 64;
  const int wn = (wid & 1) * 64;

  // Stage group scales transposed: Ws[g][col] = wsc[(bn0+col)*32 + g].
  {
    const float* src = wsc + (size_t)bn0 * NKT;
    const int u0 = tid * 16;
    const int col = u0 >> 5;
    const int g0 = u0 & 31;
    f32x4 t0 = *(const f32x4*)(src + u0);
    f32x4 t1 = *(const f32x4*)(src + u0 + 4);
    f32x4 t2 = *(const f32x4*)(src + u0 + 8);
    f32x4 t3 = *(const f32x4*)(src + u0 + 12);
#pragma unroll
    for (int j = 0; j < 4; ++j) {
      Ws[(g0 + j) * BN + col] = t0[j];
      Ws[(g0 + 4 + j) * BN + col] = t1[j];
      Ws[(g0 + 8 + j) * BN + col] = t2[j];
      Ws[(g0 + 12 + j) * BN + col] = t3[j];
    }
  }

  f32x4 facc[4][4] = {};

  const int8_t* Abase = Aq + (size_t)bm0 * IN_F;
  const int8_t* Bbase = Bq + (size_t)bn0 * IN_F;
  const int srow = tid >> 3;           // 0..31
  const int kbp = (tid & 7) << 4;      // 0..112

  for (int kt = 0; kt < NKT; ++kt) {
    __syncthreads();                   // previous tile fully consumed (covers Ws on kt=0)
#pragma unroll
    for (int p = 0; p < 4; ++p) {
      const int row = p * 32 + srow;
      const int kb = kbp ^ ((row & 7) << 4);   // pre-swizzle the SOURCE
      __builtin_amdgcn_global_load_lds(
          (const __attribute__((address_space(1))) void*)(Abase + (size_t)row * IN_F + kt * BK + kb),
          (__attribute__((address_space(3))) void*)(As + p * 4096 + wid * 1024), 16, 0, 0);
    }
#pragma unroll
    for (int p = 0; p < 4; ++p) {
      const int row = p * 32 + srow;
      const int kb = kbp ^ ((row & 7) << 4);
      __builtin_amdgcn_global_load_lds(
          (const __attribute__((address_space(1))) void*)(Bbase + (size_t)row * IN_F + kt * BK + kb),
          (__attribute__((address_space(3))) void*)(Bs + p * 4096 + wid * 1024), 16, 0, 0);
    }
    __syncthreads();                   // staging drained (compiler emits vmcnt(0) before barrier)

    i32x4 iacc[4][4] = {};
#pragma unroll
    for (int kk = 0; kk < 2; ++kk) {
      const int s = kk * 64 + (lane >> 4) * 16;
      i32x4 af[4], bf[4];
#pragma unroll
      for (int i = 0; i < 4; ++i) {
        const int r = wm + i * 16 + (lane & 15);
        af[i] = *(const i32x4*)(As + r * BK + (s ^ ((r & 7) << 4)));
      }
#pragma unroll
      for (int j = 0; j < 4; ++j) {
        const int c = wn + j * 16 + (lane & 15);
        bf[j] = *(const i32x4*)(Bs + c * BK + (s ^ ((c & 7) << 4)));
      }
#pragma unroll
      for (int i = 0; i < 4; ++i)
#pragma unroll
        for (int j = 0; j < 4; ++j)
          iacc[i][j] = __builtin_amdgcn_mfma_i32_16x16x64_i8(af[i], bf[j], iacc[i][j], 0, 0, 0);
    }

    // per-group fp32 scale-accumulate: facc += ws[n, kt] * (float)iacc
#pragma unroll
    for (int j = 0; j < 4; ++j) {
      const float wsj = Ws[kt * BN + wn + j * 16 + (lane & 15)];
#pragma unroll
      for (int i = 0; i < 4; ++i)
#pragma unroll
        for (int e = 0; e < 4; ++e)
          facc[i][j][e] += wsj * (float)iacc[i][j][e];
    }
  }

  // Epilogue: out[m][n] = act_scale[m] * facc + bias[n]
  // C/D layout: col = lane&15, row = (lane>>4)*4 + e
  const int r0 = (lane >> 4) * 4;
  const int cl = lane & 15;
#pragma unroll
  for (int i = 0; i < 4; ++i) {
#pragma unroll
    for (int e = 0; e < 4; ++e) {
      const int m = bm0 + wm + i * 16 + r0 + e;
      const float a = asc[m];
      float* orow = out + (size_t)m * OUT_F + bn0 + wn;
#pragma unroll
      for (int j = 0; j < 4; ++j) {
        const int n = j * 16 + cl;
        orow[n] = facc[i][j][e] * a + bias[bn0 + wn + n];
      }
    }
  }
}

extern "C" void kernel_launch(void* const* d_in, const int* in_sizes, int n_in,
                              void* d_out, int out_size, void* d_ws, size_t ws_size,
                              hipStream_t stream) {
  const float* x = (const float*)d_in[0];
  const int* qw = (const int*)d_in[1];
  const float* wsc = (const float*)d_in[2];
  const int* wz = (const int*)d_in[3];
  const float* bias = (const float*)d_in[4];
  float* out = (float*)d_out;

  const int tokens = in_sizes[0] / IN_F;  // 8192

  // ws layout: W' int8 [OUT_F*IN_F] | q int8 [tokens*IN_F] | scales f32 [tokens]
  int8_t* w8 = (int8_t*)d_ws;
  int8_t* q8 = w8 + (size_t)OUT_F * IN_F;
  float* sc = (float*)(q8 + (size_t)tokens * IN_F);

  act_quant_kernel<<<tokens, 256, 0, stream>>>(x, q8, sc);
  unpack_kernel<<<(OUT_F * IN_F / 2 / 8) / 256, 256, 0, stream>>>(qw, wz, w8);
  gemm_kernel<<<dim3(OUT_F / BN, tokens / BM), 256, 0, stream>>>(q8, w8, sc, wsc, bias, out);
}